// Round 12
// baseline (153.137 us; speedup 1.0000x reference)
//
#include <hip/hip_runtime.h>
#include <hip/hip_bf16.h>
#include <math.h>

// ScaledDotProductAttention, masked_softmax semantics (clip ±15, mask-mult,
// exp(x - max), re-mask, /(sum+1e-6)). B=16, L=2048, D=64, TEMP=8.
//
// Round-12 = Round-11 (176->143us via NT attn/out stores) + ONE change:
// pass-1 mask prefetch deepened to 4 tiles (4 rotating register sets,
// loop unrolled x4). Theory: pass 1 is a 268MB mask stream; depth-1
// prefetch (~2 tile-times slack) starves MLP at 2 waves/SIMD; depth-4
// doubles mask bytes in flight.

typedef __bf16 bf16x8v __attribute__((ext_vector_type(8)));
typedef __bf16 bf16x4v __attribute__((ext_vector_type(4)));
typedef __bf16 bf16x2v __attribute__((ext_vector_type(2)));
typedef float  f32x4   __attribute__((ext_vector_type(4)));
typedef int    i32x4   __attribute__((ext_vector_type(4)));

#define B_  16
#define L_  2048
#define D_  64
#define NKC 32

// swizzled byte offset within a [rows][64] bf16 tile (128 B per row)
__device__ __forceinline__ int swz(int row, int colb) {
    return (row * 128 + colb) ^ ((row & 7) << 4);
}
// swizzled byte offset within a [16 rows][64 f32] tile (256 B per row)
__device__ __forceinline__ int swzF(int row, int colb) {
    return row * 256 + (colb ^ ((row & 7) << 4));
}

// barrier WITHOUT the vmcnt(0) drain
__device__ __forceinline__ void bar() {
    asm volatile("s_waitcnt lgkmcnt(0)" ::: "memory");
    __builtin_amdgcn_s_barrier();
}

__global__ __launch_bounds__(256, 2)
void sdpa_kernel(const float* __restrict__ qg,
                 const float* __restrict__ kg,
                 const float* __restrict__ vg,
                 const int*   __restrict__ mg,
                 float* __restrict__ outg,    // [B][L][D]
                 float* __restrict__ attng)   // [B][L][L]
{
    __shared__ __align__(16) char KtB[2][8192];   // K tile bf16 [64][64] swz
    __shared__ __align__(16) char VtB[2][8192];   // V^T tile bf16 [d][k] swz
    __shared__ __align__(16) char PwB[4][2048];   // per-wave P bf16 [16][64] swz
    __shared__ __align__(16) char PfB[4][4096];   // per-wave P f32 [16][64] swzF
    __shared__ unsigned short Ml[NKC][256];       // mask bits [kc][thread]
    __shared__ unsigned Mn32[4][64];              // per-wave nibble xchg

    const int t  = threadIdx.x;
    const int w  = t >> 6;
    const int l  = t & 63;
    const int lq = l & 15;        // q within wave tile (MFMA col / A row)
    const int g  = l >> 4;        // 4-lane group

    // XCD-grouping remap: 512 blocks = 8 XCDs x 64
    const int bid  = blockIdx.x;
    const int virt = (bid & 7) * 64 + (bid >> 3);
    const int b  = virt >> 5;
    const int q0 = (virt & 31) * 64;
    const int qi = q0 + w * 16 + lq;

    const size_t kvbase = (size_t)b * (L_ * D_);
    const size_t qwrow  = (size_t)b * L_ + q0 + w * 16; // wave's first q row

    // ---- Q fragments (B operand), 1/8 temperature folded in ----
    bf16x8v qf0, qf1;
    {
        const float* qrow = qg + ((size_t)b * L_ + qi) * D_;
        const f32x4* p0 = (const f32x4*)(qrow + g * 8);
        const f32x4* p1 = (const f32x4*)(qrow + 32 + g * 8);
        f32x4 x0 = p0[0], x1 = p0[1], x2 = p1[0], x3 = p1[1];
        #pragma unroll
        for (int j = 0; j < 4; ++j) {
            qf0[j]     = (__bf16)(x0[j] * 0.125f);
            qf0[4 + j] = (__bf16)(x1[j] * 0.125f);
            qf1[j]     = (__bf16)(x2[j] * 0.125f);
            qf1[4 + j] = (__bf16)(x3[j] * 0.125f);
        }
    }

    // ---- staging geometry ----
    const int sr  = t >> 2;               // K-tile row this thread stages
    const int scb = (t & 3) * 32;         // byte col (16 bf16 = 32 B)
    const float* kbase  = kg + kvbase + (size_t)sr * D_ + (t & 3) * 16;
    const float* vbase0 = vg + kvbase + (size_t)(2 * (t & 31)) * D_ + (t >> 5) * 8;
    const int dg = t >> 5, kp = t & 31;
    // coalesced mask base: lane row = l>>4 (+4j), cols (l&15)*4
    const int* mbase = mg + (qwrow + (l >> 4)) * L_ + (l & 15) * 4;

    auto loadK = [&](int kc, f32x4& a, f32x4& bb, f32x4& c, f32x4& d) {
        const f32x4* s = (const f32x4*)(kbase + (size_t)kc * (64 * D_));
        a = s[0]; bb = s[1]; c = s[2]; d = s[3];
    };
    auto writeK = [&](char* buf, f32x4 a, f32x4 bb, f32x4 c, f32x4 d) {
        bf16x8v h0, h1;
        #pragma unroll
        for (int j = 0; j < 4; ++j) {
            h0[j] = (__bf16)a[j]; h0[4 + j] = (__bf16)bb[j];
            h1[j] = (__bf16)c[j]; h1[4 + j] = (__bf16)d[j];
        }
        *(bf16x8v*)(buf + swz(sr, scb))      = h0;
        *(bf16x8v*)(buf + swz(sr, scb + 16)) = h1;
    };
    auto loadV = [&](int kc, f32x4& a, f32x4& bb, f32x4& c, f32x4& d) {
        const float* r0 = vbase0 + (size_t)kc * (64 * D_);
        const f32x4* s0 = (const f32x4*)r0;
        const f32x4* s1 = (const f32x4*)(r0 + D_);
        a = s0[0]; bb = s0[1]; c = s1[0]; d = s1[1];
    };
    auto writeV = [&](char* buf, f32x4 a, f32x4 bb, f32x4 c, f32x4 d) {
        #pragma unroll
        for (int j = 0; j < 4; ++j) {
            bf16x2v p0; p0[0] = (__bf16)a[j];  p0[1] = (__bf16)c[j];
            *(bf16x2v*)(buf + swz(dg * 8 + j, kp * 4)) = p0;
            bf16x2v p1; p1[0] = (__bf16)bb[j]; p1[1] = (__bf16)d[j];
            *(bf16x2v*)(buf + swz(dg * 8 + 4 + j, kp * 4)) = p1;
        }
    };
    // coalesced mask load: 4 instrs, each 4 rows x 256B contiguous
    auto loadM = [&](int kc, i32x4& m0, i32x4& m1, i32x4& m2, i32x4& m3) {
        const int* p = mbase + kc * 64;
        m0 = *(const i32x4*)(p);
        m1 = *(const i32x4*)(p + 4 * L_);
        m2 = *(const i32x4*)(p + 8 * L_);
        m3 = *(const i32x4*)(p + 12 * L_);
    };

    float rS = 0.f;
    float inv = 0.f;

    auto compute1 = [&](const char* KB, int kc, i32x4 m0, i32x4 m1, i32x4 m2, i32x4 m3) {
        auto nib = [](i32x4 m) -> unsigned {
            return (m[0] ? 1u : 0u) | (m[1] ? 2u : 0u) | (m[2] ? 4u : 0u) | (m[3] ? 8u : 0u);
        };
        Mn32[w][l] = nib(m0) | (nib(m1) << 8) | (nib(m2) << 16) | (nib(m3) << 24);
        asm volatile("s_waitcnt lgkmcnt(0)" ::: "memory");  // same-wave xchg
        unsigned mbits = 0;
        const int sh = (lq >> 2) * 8;
        #pragma unroll
        for (int sub = 0; sub < 4; ++sub) {
            unsigned nb = (Mn32[w][(lq & 3) * 16 + sub * 4 + g] >> sh) & 0xFu;
            mbits |= nb << (sub * 4);
        }
        float part = 0.f;
        #pragma unroll
        for (int sub = 0; sub < 4; ++sub) {
            bf16x8v a0 = *(const bf16x8v*)(KB + swz(sub * 16 + lq, g * 16));
            bf16x8v a1 = *(const bf16x8v*)(KB + swz(sub * 16 + lq, 64 + g * 16));
            f32x4 s = {0.f, 0.f, 0.f, 0.f};
            s = __builtin_amdgcn_mfma_f32_16x16x32_bf16(a0, qf0, s, 0, 0, 0);
            s = __builtin_amdgcn_mfma_f32_16x16x32_bf16(a1, qf1, s, 0, 0, 0);
            #pragma unroll
            for (int r = 0; r < 4; ++r) {
                bool mm = (mbits >> (sub * 4 + r)) & 1u;
                float y = mm ? (fminf(fmaxf(s[r], -15.f), 15.f) - 15.f) : -1e30f;
                part += __expf(y);        // exp(-1e30) = 0
            }
        }
        rS += part;
        Ml[kc][t] = (unsigned short)mbits;
    };

    f32x4 acc[4];
    #pragma unroll
    for (int i = 0; i < 4; ++i) acc[i] = (f32x4){0.f, 0.f, 0.f, 0.f};

    auto compute2 = [&](const char* KB, const char* VB, int kc) {
        const unsigned mbits = Ml[kc][t];
        char* PFw = PfB[w];
        #pragma unroll
        for (int sub = 0; sub < 4; ++sub) {
            bf16x8v a0 = *(const bf16x8v*)(KB + swz(sub * 16 + lq, g * 16));
            bf16x8v a1 = *(const bf16x8v*)(KB + swz(sub * 16 + lq, 64 + g * 16));
            f32x4 s = {0.f, 0.f, 0.f, 0.f};
            s = __builtin_amdgcn_mfma_f32_16x16x32_bf16(a0, qf0, s, 0, 0, 0);
            s = __builtin_amdgcn_mfma_f32_16x16x32_bf16(a1, qf1, s, 0, 0, 0);
            f32x4 pv; bf16x4v pb;
            #pragma unroll
            for (int r = 0; r < 4; ++r) {
                bool mm = (mbits >> (sub * 4 + r)) & 1u;
                float y = mm ? (fminf(fmaxf(s[r], -15.f), 15.f) - 15.f) : -1e30f;
                float p = __expf(y) * inv;
                pv[r] = p; pb[r] = (__bf16)p;
            }
            *(f32x4*)(PFw + swzF(lq, (sub * 16 + g * 4) * 4)) = pv;   // f32 stage
            *(bf16x4v*)(PwB[w] + swz(lq, (sub * 16 + g * 4) * 2)) = pb;
        }
        // PV MFMAs (same-wave LDS RAW)
        #pragma unroll
        for (int ks = 0; ks < 2; ++ks) {
            bf16x8v pa = *(const bf16x8v*)(PwB[w] + swz(lq, ks * 64 + g * 16));
            #pragma unroll
            for (int dt = 0; dt < 4; ++dt) {
                bf16x8v vb = *(const bf16x8v*)(VB + swz(dt * 16 + lq, ks * 64 + g * 16));
                acc[dt] = __builtin_amdgcn_mfma_f32_16x16x32_bf16(pa, vb, acc[dt], 0, 0, 0);
            }
        }
        // coalesced NON-TEMPORAL attn store: 4 instrs x (4 rows x 256 B)
        #pragma unroll
        for (int j = 0; j < 4; ++j) {
            const int row = (l >> 4) + 4 * j;
            const int col = (l & 15) * 4;
            f32x4 o = *(const f32x4*)(PFw + swzF(row, col * 4));
            __builtin_nontemporal_store(o, (f32x4*)(attng + (qwrow + row) * L_ + kc * 64 + col));
        }
    };

    // prefetch register sets: K/V double sets, mask QUAD sets (depth 4)
    f32x4 kA0, kA1, kA2, kA3, kB0, kB1, kB2, kB3;
    f32x4 vA0, vA1, vA2, vA3, vB0, vB1, vB2, vB3;
    i32x4 mA0, mA1, mA2, mA3, mB0, mB1, mB2, mB3;
    i32x4 mC0, mC1, mC2, mC3, mD0, mD1, mD2, mD3;

    // ======================= PASS 1: masked exp-sum =======================
    loadK(0, kA0, kA1, kA2, kA3);
    loadM(0, mA0, mA1, mA2, mA3);
    loadM(1, mB0, mB1, mB2, mB3);
    writeK(KtB[0], kA0, kA1, kA2, kA3);      // one-time stall
    loadK(1, kB0, kB1, kB2, kB3);
    loadM(2, mC0, mC1, mC2, mC3);
    loadM(3, mD0, mD1, mD2, mD3);
    bar();
    #pragma unroll 1
    for (int kc = 0; kc < NKC; kc += 4) {
        // step 0: compute tile kc (buf0, mask A)
        { int kn = (kc + 2 < NKC) ? kc + 2 : NKC - 1; loadK(kn, kA0, kA1, kA2, kA3); }
        compute1(KtB[0], kc, mA0, mA1, mA2, mA3);
        { int kn = (kc + 4 < NKC) ? kc + 4 : NKC - 1; loadM(kn, mA0, mA1, mA2, mA3); }
        writeK(KtB[1], kB0, kB1, kB2, kB3);
        bar();
        // step 1: tile kc+1 (buf1, mask B)
        { int kn = (kc + 3 < NKC) ? kc + 3 : NKC - 1; loadK(kn, kB0, kB1, kB2, kB3); }
        compute1(KtB[1], kc + 1, mB0, mB1, mB2, mB3);
        { int kn = (kc + 5 < NKC) ? kc + 5 : NKC - 1; loadM(kn, mB0, mB1, mB2, mB3); }
        writeK(KtB[0], kA0, kA1, kA2, kA3);
        bar();
        // step 2: tile kc+2 (buf0, mask C)
        { int kn = (kc + 4 < NKC) ? kc + 4 : NKC - 1; loadK(kn, kA0, kA1, kA2, kA3); }
        compute1(KtB[0], kc + 2, mC0, mC1, mC2, mC3);
        { int kn = (kc + 6 < NKC) ? kc + 6 : NKC - 1; loadM(kn, mC0, mC1, mC2, mC3); }
        writeK(KtB[1], kB0, kB1, kB2, kB3);
        bar();
        // step 3: tile kc+3 (buf1, mask D)
        { int kn = (kc + 5 < NKC) ? kc + 5 : NKC - 1; loadK(kn, kB0, kB1, kB2, kB3); }
        compute1(KtB[1], kc + 3, mD0, mD1, mD2, mD3);
        { int kn = (kc + 7 < NKC) ? kc + 7 : NKC - 1; loadM(kn, mD0, mD1, mD2, mD3); }
        writeK(KtB[0], kA0, kA1, kA2, kA3);
        bar();
    }

    // issue pass-2 first tiles, then reduce (overlap load latency)
    loadK(0, kA0, kA1, kA2, kA3);
    loadV(0, vA0, vA1, vA2, vA3);
    rS += __shfl_xor(rS, 16, 64);
    rS += __shfl_xor(rS, 32, 64);
    inv = 1.f / (rS + 1e-6f);

    // ======================= PASS 2: attn + PV =======================
    writeK(KtB[0], kA0, kA1, kA2, kA3);
    writeV(VtB[0], vA0, vA1, vA2, vA3);
    loadK(1, kB0, kB1, kB2, kB3);
    loadV(1, vB0, vB1, vB2, vB3);
    bar();
    #pragma unroll 1
    for (int kc = 0; kc < NKC; kc += 2) {
        { int kn = (kc + 2 < NKC) ? kc + 2 : NKC - 1;
          loadK(kn, kA0, kA1, kA2, kA3); loadV(kn, vA0, vA1, vA2, vA3); }
        compute2(KtB[0], VtB[0], kc);
        writeK(KtB[1], kB0, kB1, kB2, kB3);
        writeV(VtB[1], vB0, vB1, vB2, vB3);
        bar();
        { int kn = (kc + 3 < NKC) ? kc + 3 : NKC - 1;
          loadK(kn, kB0, kB1, kB2, kB3); loadV(kn, vB0, vB1, vB2, vB3); }
        compute2(KtB[1], VtB[1], kc + 1);
        writeK(KtB[0], kA0, kA1, kA2, kA3);
        writeV(VtB[0], vA0, vA1, vA2, vA3);
        bar();
    }

    // epilogue: acc row = q-local (g*4+r), col = d (dt*16+lq); NT stores
    #pragma unroll
    for (int dt = 0; dt < 4; ++dt) {
        #pragma unroll
        for (int r = 0; r < 4; ++r) {
            __builtin_nontemporal_store(acc[dt][r],
                outg + ((size_t)b * L_ + (q0 + w * 16 + g * 4 + r)) * D_ + dt * 16 + lq);
        }
    }
}

extern "C" void kernel_launch(void* const* d_in, const int* in_sizes, int n_in,
                              void* d_out, int out_size, void* d_ws, size_t ws_size,
                              hipStream_t stream) {
    (void)in_sizes; (void)n_in; (void)out_size; (void)d_ws; (void)ws_size;
    const float* q = (const float*)d_in[0];
    const float* k = (const float*)d_in[1];
    const float* v = (const float*)d_in[2];
    const int*   m = (const int*)d_in[3];
    float* out  = (float*)d_out;
    float* attn = out + (size_t)B_ * L_ * D_;
    dim3 grid(B_ * (L_ / 64));   // 512
    dim3 block(256);
    hipLaunchKernelGGL(sdpa_kernel, grid, block, 0, stream, q, k, v, m, out, attn);
}

// Round 14
// 148.882 us; speedup vs baseline: 1.0286x; 1.0286x over previous
//
#include <hip/hip_runtime.h>
#include <hip/hip_bf16.h>
#include <math.h>

// ScaledDotProductAttention, masked_softmax semantics (clip ±15, mask-mult,
// exp(x - max), re-mask, /(sum+1e-6)). B=16, L=2048, D=64, TEMP=8.
//
// Round-14 = Round-13 (NT stores + 1KB-aggregated attn flush) with the LDS
// overlap bug fixed: Mn32 (pass-1 nibble-exchange scratch) now aliases the
// Pacc region (pass-2 only) instead of overlapping Ml's last 1KB. Arena
// stays 80KB -> 2 blocks/CU.

typedef __bf16 bf16x8v __attribute__((ext_vector_type(8)));
typedef __bf16 bf16x4v __attribute__((ext_vector_type(4)));
typedef __bf16 bf16x2v __attribute__((ext_vector_type(2)));
typedef float  f32x4   __attribute__((ext_vector_type(4)));
typedef int    i32x4   __attribute__((ext_vector_type(4)));

#define B_  16
#define L_  2048
#define D_  64
#define NKC 32

// swizzled byte offset within a [rows][64] bf16 tile (128 B per row)
__device__ __forceinline__ int swz(int row, int colb) {
    return (row * 128 + colb) ^ ((row & 7) << 4);
}
// barrier WITHOUT vmcnt drain (prefetch loads stay in flight)
__device__ __forceinline__ void bar() {
    asm volatile("s_waitcnt lgkmcnt(0)" ::: "memory");
    __builtin_amdgcn_s_barrier();
}

__global__ __launch_bounds__(256, 2)
void sdpa_kernel(const float* __restrict__ qg,
                 const float* __restrict__ kg,
                 const float* __restrict__ vg,
                 const int*   __restrict__ mg,
                 float* __restrict__ outg,    // [B][L][D]
                 float* __restrict__ attng)   // [B][L][L]
{
    // 80KB arena: Kt dbuf 16K | Vt dbuf 16K | Pacc 4x8K | Ml u16 16K
    // Mn32 (pass-1 only) aliases Pacc (pass-2 only) -- no overlap with Ml.
    __shared__ __align__(16) char arena[81920];
    char* KtB0 = arena;
    char* KtB1 = arena + 8192;
    char* VtB0 = arena + 16384;
    char* VtB1 = arena + 24576;
    char* Pacc = arena + 32768;                       // [wave][16 q][256 k] bf16 swz
    unsigned short* Ml = (unsigned short*)(arena + 65536);  // [kc][thread] 16KB
    unsigned* Mn32 = (unsigned*)(arena + 32768);      // pass-1 scratch, aliases Pacc

    const int t  = threadIdx.x;
    const int w  = t >> 6;
    const int l  = t & 63;
    const int lq = l & 15;        // q within wave tile (MFMA col / A row)
    const int g  = l >> 4;        // 4-lane group

    // XCD remap: 512 blocks = 8 XCDs x 64 (bijective)
    const int bid  = blockIdx.x;
    const int virt = (bid & 7) * 64 + (bid >> 3);
    const int b  = virt >> 5;
    const int q0 = (virt & 31) * 64;
    const int qi = q0 + w * 16 + lq;

    const size_t kvbase = (size_t)b * (L_ * D_);
    const size_t qwrow  = (size_t)b * L_ + q0 + w * 16;  // wave's first q row

    // ---- Q fragments (B operand), 1/8 temperature folded in ----
    bf16x8v qf0, qf1;
    {
        const float* qrow = qg + ((size_t)b * L_ + qi) * D_;
        const f32x4* p0 = (const f32x4*)(qrow + g * 8);
        const f32x4* p1 = (const f32x4*)(qrow + 32 + g * 8);
        f32x4 x0 = p0[0], x1 = p0[1], x2 = p1[0], x3 = p1[1];
        #pragma unroll
        for (int j = 0; j < 4; ++j) {
            qf0[j]     = (__bf16)(x0[j] * 0.125f);
            qf0[4 + j] = (__bf16)(x1[j] * 0.125f);
            qf1[j]     = (__bf16)(x2[j] * 0.125f);
            qf1[4 + j] = (__bf16)(x3[j] * 0.125f);
        }
    }

    // ---- staging geometry ----
    const int sr  = t >> 2;               // K-tile row this thread stages
    const int scb = (t & 3) * 32;         // byte col (16 bf16 = 32 B)
    const float* kbase  = kg + kvbase + (size_t)sr * D_ + (t & 3) * 16;
    const float* vbase0 = vg + kvbase + (size_t)(2 * (t & 31)) * D_ + (t >> 5) * 8;
    const int dg = t >> 5, kp = t & 31;
    // coalesced mask producer base: rows qwrow+(l>>4)+4j, cols (l&15)*4
    const int* mbase = mg + (qwrow + (l >> 4)) * L_ + (l & 15) * 4;

    auto loadK = [&](int kc, f32x4* r) {
        const f32x4* s = (const f32x4*)(kbase + (size_t)kc * (64 * D_));
        #pragma unroll
        for (int j = 0; j < 4; ++j) r[j] = s[j];
    };
    auto writeK = [&](char* buf, const f32x4* r) {
        bf16x8v h0, h1;
        #pragma unroll
        for (int j = 0; j < 4; ++j) {
            h0[j] = (__bf16)r[0][j]; h0[4 + j] = (__bf16)r[1][j];
            h1[j] = (__bf16)r[2][j]; h1[4 + j] = (__bf16)r[3][j];
        }
        *(bf16x8v*)(buf + swz(sr, scb))      = h0;
        *(bf16x8v*)(buf + swz(sr, scb + 16)) = h1;
    };
    auto loadV = [&](int kc, f32x4* r) {
        const float* r0 = vbase0 + (size_t)kc * (64 * D_);
        const f32x4* s0 = (const f32x4*)r0;
        const f32x4* s1 = (const f32x4*)(r0 + D_);
        r[0] = s0[0]; r[1] = s0[1]; r[2] = s1[0]; r[3] = s1[1];
    };
    auto writeV = [&](char* buf, const f32x4* r) {
        #pragma unroll
        for (int j = 0; j < 4; ++j) {
            bf16x2v p0; p0[0] = (__bf16)r[0][j]; p0[1] = (__bf16)r[2][j];
            *(bf16x2v*)(buf + swz(dg * 8 + j, kp * 4)) = p0;
            bf16x2v p1; p1[0] = (__bf16)r[1][j]; p1[1] = (__bf16)r[3][j];
            *(bf16x2v*)(buf + swz(dg * 8 + 4 + j, kp * 4)) = p1;
        }
    };
    auto loadM = [&](int kc, i32x4* m) {
        const int* p = mbase + kc * 64;
        m[0] = *(const i32x4*)(p);
        m[1] = *(const i32x4*)(p + 4 * L_);
        m[2] = *(const i32x4*)(p + 8 * L_);
        m[3] = *(const i32x4*)(p + 12 * L_);
    };
    // intra-wave transpose of producer-layout mask bits -> consumer mbits
    auto xchg = [&](const i32x4* m) -> unsigned {
        auto nib = [](i32x4 v) -> unsigned {
            return (v[0] ? 1u : 0u) | (v[1] ? 2u : 0u) | (v[2] ? 4u : 0u) | (v[3] ? 8u : 0u);
        };
        Mn32[w * 64 + l] = nib(m[0]) | (nib(m[1]) << 8) | (nib(m[2]) << 16) | (nib(m[3]) << 24);
        asm volatile("s_waitcnt lgkmcnt(0)" ::: "memory");  // same-wave xchg
        unsigned mb = 0;
        const int sh = (lq >> 2) * 8;
        #pragma unroll
        for (int sub = 0; sub < 4; ++sub) {
            unsigned v = Mn32[w * 64 + (lq & 3) * 16 + sub * 4 + g];
            mb |= ((v >> sh) & 0xFu) << (sub * 4);
        }
        return mb;
    };

    float rS = 0.f;
    float inv = 0.f;
    char* PW = Pacc + w * 8192;

    auto compute1 = [&](const char* KB, int kc, unsigned mbits) {
        Ml[kc * 256 + t] = (unsigned short)mbits;
        float part = 0.f;
        #pragma unroll
        for (int sub = 0; sub < 4; ++sub) {
            bf16x8v a0 = *(const bf16x8v*)(KB + swz(sub * 16 + lq, g * 16));
            bf16x8v a1 = *(const bf16x8v*)(KB + swz(sub * 16 + lq, 64 + g * 16));
            f32x4 s = {0.f, 0.f, 0.f, 0.f};
            s = __builtin_amdgcn_mfma_f32_16x16x32_bf16(a0, qf0, s, 0, 0, 0);
            s = __builtin_amdgcn_mfma_f32_16x16x32_bf16(a1, qf1, s, 0, 0, 0);
            #pragma unroll
            for (int r = 0; r < 4; ++r) {
                bool mm = (mbits >> (sub * 4 + r)) & 1u;
                float y = mm ? (fminf(fmaxf(s[r], -15.f), 15.f) - 15.f) : -1e30f;
                part += __expf(y);        // exp(-1e30) = 0
            }
        }
        rS += part;
    };

    f32x4 acc[4];
    #pragma unroll
    for (int i = 0; i < 4; ++i) acc[i] = (f32x4){0.f, 0.f, 0.f, 0.f};

    auto compute2 = [&](const char* KB, const char* VB, int kc) {
        const unsigned mbits = Ml[kc * 256 + t];
        const int tt = kc & 3;
        #pragma unroll
        for (int sub = 0; sub < 4; ++sub) {
            bf16x8v a0 = *(const bf16x8v*)(KB + swz(sub * 16 + lq, g * 16));
            bf16x8v a1 = *(const bf16x8v*)(KB + swz(sub * 16 + lq, 64 + g * 16));
            f32x4 s = {0.f, 0.f, 0.f, 0.f};
            s = __builtin_amdgcn_mfma_f32_16x16x32_bf16(a0, qf0, s, 0, 0, 0);
            s = __builtin_amdgcn_mfma_f32_16x16x32_bf16(a1, qf1, s, 0, 0, 0);
            bf16x4v pb;
            #pragma unroll
            for (int r = 0; r < 4; ++r) {
                bool mm = (mbits >> (sub * 4 + r)) & 1u;
                float y = mm ? (fminf(fmaxf(s[r], -15.f), 15.f) - 15.f) : -1e30f;
                pb[r] = (__bf16)(__expf(y) * inv);
            }
            *(bf16x4v*)(PW + lq * 512 + ((tt * 128 + sub * 32 + g * 8) ^ ((lq & 7) << 4))) = pb;
        }
        // PV MFMAs: A-fragments straight from the Pacc slice (same-wave RAW)
        #pragma unroll
        for (int ks = 0; ks < 2; ++ks) {
            bf16x8v pa = *(const bf16x8v*)(PW + lq * 512 +
                                           ((tt * 128 + ks * 64 + g * 16) ^ ((lq & 7) << 4)));
            #pragma unroll
            for (int dt = 0; dt < 4; ++dt) {
                bf16x8v vb = *(const bf16x8v*)(VB + swz(dt * 16 + lq, ks * 64 + g * 16));
                acc[dt] = __builtin_amdgcn_mfma_f32_16x16x32_bf16(pa, vb, acc[dt], 0, 0, 0);
            }
        }
    };

    // flush one super-chunk (4 tiles, 256 k): 16 rows x 1KB contiguous NT
    auto flushA = [&](int sc) {
        #pragma unroll
        for (int r = 0; r < 16; ++r) {
            bf16x4v pq = *(const bf16x4v*)(PW + r * 512 + ((l * 8) ^ ((r & 7) << 4)));
            f32x4 o;
            #pragma unroll
            for (int c = 0; c < 4; ++c) o[c] = (float)pq[c];
            __builtin_nontemporal_store(o,
                (f32x4*)(attng + (qwrow + r) * L_ + sc * 256 + l * 4));
        }
    };

    // prefetch register sets (A = even tiles, B = odd tiles)
    f32x4 kA[4], kB[4], vA[4], vB[4];
    i32x4 mA[4], mB[4];

    // ======================= PASS 1: masked exp-sum =======================
    loadK(0, kA);
    loadM(0, mA);
    writeK(KtB0, kA);                        // one-time stall
    loadK(1, kB);
    loadM(1, mB);
    bar();
    #pragma unroll 1
    for (int kc = 0; kc < NKC; kc += 2) {
        { int kn = (kc + 2 < NKC) ? kc + 2 : NKC - 1; loadK(kn, kA); }
        { unsigned mb = xchg(mA);
          { int kn = (kc + 2 < NKC) ? kc + 2 : NKC - 1; loadM(kn, mA); }
          compute1(KtB0, kc, mb); }
        writeK(KtB1, kB);                    // tile kc+1 (regs from last iter)
        bar();
        { int kn = (kc + 3 < NKC) ? kc + 3 : NKC - 1; loadK(kn, kB); }
        { unsigned mb = xchg(mB);
          { int kn = (kc + 3 < NKC) ? kc + 3 : NKC - 1; loadM(kn, mB); }
          compute1(KtB1, kc + 1, mb); }
        writeK(KtB0, kA);                    // tile kc+2
        bar();
    }

    // issue pass-2 first tiles, then reduce (overlap load latency)
    loadK(0, kA);
    loadV(0, vA);
    rS += __shfl_xor(rS, 16, 64);
    rS += __shfl_xor(rS, 32, 64);
    inv = 1.f / (rS + 1e-6f);

    // ======================= PASS 2: attn + PV =======================
    bar();                                   // all waves done with Mn32 (Pacc alias)
    writeK(KtB0, kA);
    writeV(VtB0, vA);
    loadK(1, kB);
    loadV(1, vB);
    bar();
    #pragma unroll 1
    for (int kc = 0; kc < NKC; kc += 2) {
        { int kn = (kc + 2 < NKC) ? kc + 2 : NKC - 1; loadK(kn, kA); loadV(kn, vA); }
        compute2(KtB0, VtB0, kc);
        writeK(KtB1, kB);
        writeV(VtB1, vB);
        bar();
        { int kn = (kc + 3 < NKC) ? kc + 3 : NKC - 1; loadK(kn, kB); loadV(kn, vB); }
        compute2(KtB1, VtB1, kc + 1);
        if ((kc & 3) == 2) flushA((kc + 1) >> 2);   // tiles sc*4..sc*4+3 done
        writeK(KtB0, kA);
        writeV(VtB0, vA);
        bar();
    }

    // epilogue: acc row = q-local (g*4+r), col = d (dt*16+lq); NT stores
    #pragma unroll
    for (int dt = 0; dt < 4; ++dt) {
        #pragma unroll
        for (int r = 0; r < 4; ++r) {
            __builtin_nontemporal_store(acc[dt][r],
                outg + (qwrow + g * 4 + r) * D_ + dt * 16 + lq);
        }
    }
}

extern "C" void kernel_launch(void* const* d_in, const int* in_sizes, int n_in,
                              void* d_out, int out_size, void* d_ws, size_t ws_size,
                              hipStream_t stream) {
    (void)in_sizes; (void)n_in; (void)out_size; (void)d_ws; (void)ws_size;
    const float* q = (const float*)d_in[0];
    const float* k = (const float*)d_in[1];
    const float* v = (const float*)d_in[2];
    const int*   m = (const int*)d_in[3];
    float* out  = (float*)d_out;
    float* attn = out + (size_t)B_ * L_ * D_;
    dim3 grid(B_ * (L_ / 64));   // 512
    dim3 block(256);
    hipLaunchKernelGGL(sdpa_kernel, grid, block, 0, stream, q, k, v, m, out, attn);
}

// Round 16
// 143.224 us; speedup vs baseline: 1.0692x; 1.0395x over previous
//
#include <hip/hip_runtime.h>
#include <hip/hip_bf16.h>
#include <math.h>

// ScaledDotProductAttention, masked_softmax semantics (clip ±15, mask-mult,
// exp(x - max), re-mask, /(sum+1e-6)). B=16, L=2048, D=64, TEMP=8.
//
// Round-16 = Round-15 (PV moved to pass 1 with unnormalized e via linearity;
// pass 2 = pure attn-write stream) with the epilogue bug fixed: acc[dt][r]
// belongs to q-row g*4+r, so O must scale by THAT row's inv --
// __shfl(inv, g*4+r) -- not this lane's (row lq) inv.

typedef __bf16 bf16x8v __attribute__((ext_vector_type(8)));
typedef __bf16 bf16x4v __attribute__((ext_vector_type(4)));
typedef __bf16 bf16x2v __attribute__((ext_vector_type(2)));
typedef float  f32x4   __attribute__((ext_vector_type(4)));
typedef int    i32x4   __attribute__((ext_vector_type(4)));

#define B_  16
#define L_  2048
#define D_  64
#define NKC 32

// swizzled byte offset within a [rows][64] bf16 tile (128 B per row)
__device__ __forceinline__ int swz(int row, int colb) {
    return (row * 128 + colb) ^ ((row & 7) << 4);
}
// swizzled byte offset within a [16 rows][64 f32] tile (256 B per row)
__device__ __forceinline__ int swzF(int row, int colb) {
    return row * 256 + (colb ^ ((row & 7) << 4));
}

// barrier WITHOUT the vmcnt(0) drain
__device__ __forceinline__ void bar() {
    asm volatile("s_waitcnt lgkmcnt(0)" ::: "memory");
    __builtin_amdgcn_s_barrier();
}

__global__ __launch_bounds__(256, 2)
void sdpa_kernel(const float* __restrict__ qg,
                 const float* __restrict__ kg,
                 const float* __restrict__ vg,
                 const int*   __restrict__ mg,
                 float* __restrict__ outg,    // [B][L][D]
                 float* __restrict__ attng)   // [B][L][L]
{
    __shared__ __align__(16) char KtB[2][8192];   // K tile bf16 [64][64] swz
    __shared__ __align__(16) char VtB[2][8192];   // V^T tile bf16 [d][k] swz
    __shared__ __align__(16) char PwB[4][2048];   // per-wave e bf16 [16][64] swz
    __shared__ __align__(16) char PfB[4][4096];   // per-wave attn f32 [16][64] swzF
    __shared__ unsigned short Ml[NKC][256];       // mask bits [kc][thread]
    __shared__ unsigned Mn32[4][64];              // per-wave nibble xchg

    const int t  = threadIdx.x;
    const int w  = t >> 6;
    const int l  = t & 63;
    const int lq = l & 15;        // q within wave tile (MFMA col / A row)
    const int g  = l >> 4;        // 4-lane group

    // XCD-grouping remap: 512 blocks = 8 XCDs x 64
    const int bid  = blockIdx.x;
    const int virt = (bid & 7) * 64 + (bid >> 3);
    const int b  = virt >> 5;
    const int q0 = (virt & 31) * 64;
    const int qi = q0 + w * 16 + lq;

    const size_t kvbase = (size_t)b * (L_ * D_);
    const size_t qwrow  = (size_t)b * L_ + q0 + w * 16; // wave's first q row

    // ---- Q fragments (B operand), 1/8 temperature folded in ----
    bf16x8v qf0, qf1;
    {
        const float* qrow = qg + ((size_t)b * L_ + qi) * D_;
        const f32x4* p0 = (const f32x4*)(qrow + g * 8);
        const f32x4* p1 = (const f32x4*)(qrow + 32 + g * 8);
        f32x4 x0 = p0[0], x1 = p0[1], x2 = p1[0], x3 = p1[1];
        #pragma unroll
        for (int j = 0; j < 4; ++j) {
            qf0[j]     = (__bf16)(x0[j] * 0.125f);
            qf0[4 + j] = (__bf16)(x1[j] * 0.125f);
            qf1[j]     = (__bf16)(x2[j] * 0.125f);
            qf1[4 + j] = (__bf16)(x3[j] * 0.125f);
        }
    }

    // ---- staging geometry ----
    const int sr  = t >> 2;               // K-tile row this thread stages
    const int scb = (t & 3) * 32;         // byte col (16 bf16 = 32 B)
    const float* kbase  = kg + kvbase + (size_t)sr * D_ + (t & 3) * 16;
    const float* vbase0 = vg + kvbase + (size_t)(2 * (t & 31)) * D_ + (t >> 5) * 8;
    const int dg = t >> 5, kp = t & 31;
    // coalesced mask base: lane row = l>>4 (+4j), cols (l&15)*4
    const int* mbase = mg + (qwrow + (l >> 4)) * L_ + (l & 15) * 4;

    auto loadK = [&](int kc, f32x4& a, f32x4& bb, f32x4& c, f32x4& d) {
        const f32x4* s = (const f32x4*)(kbase + (size_t)kc * (64 * D_));
        a = s[0]; bb = s[1]; c = s[2]; d = s[3];
    };
    auto writeK = [&](char* buf, f32x4 a, f32x4 bb, f32x4 c, f32x4 d) {
        bf16x8v h0, h1;
        #pragma unroll
        for (int j = 0; j < 4; ++j) {
            h0[j] = (__bf16)a[j]; h0[4 + j] = (__bf16)bb[j];
            h1[j] = (__bf16)c[j]; h1[4 + j] = (__bf16)d[j];
        }
        *(bf16x8v*)(buf + swz(sr, scb))      = h0;
        *(bf16x8v*)(buf + swz(sr, scb + 16)) = h1;
    };
    auto loadV = [&](int kc, f32x4& a, f32x4& bb, f32x4& c, f32x4& d) {
        const float* r0 = vbase0 + (size_t)kc * (64 * D_);
        const f32x4* s0 = (const f32x4*)r0;
        const f32x4* s1 = (const f32x4*)(r0 + D_);
        a = s0[0]; bb = s0[1]; c = s1[0]; d = s1[1];
    };
    auto writeV = [&](char* buf, f32x4 a, f32x4 bb, f32x4 c, f32x4 d) {
        #pragma unroll
        for (int j = 0; j < 4; ++j) {
            bf16x2v p0; p0[0] = (__bf16)a[j];  p0[1] = (__bf16)c[j];
            *(bf16x2v*)(buf + swz(dg * 8 + j, kp * 4)) = p0;
            bf16x2v p1; p1[0] = (__bf16)bb[j]; p1[1] = (__bf16)d[j];
            *(bf16x2v*)(buf + swz(dg * 8 + 4 + j, kp * 4)) = p1;
        }
    };
    // coalesced mask load: 4 instrs, each 4 rows x 256B contiguous
    auto loadM = [&](int kc, i32x4& m0, i32x4& m1, i32x4& m2, i32x4& m3) {
        const int* p = mbase + kc * 64;
        m0 = *(const i32x4*)(p);
        m1 = *(const i32x4*)(p + 4 * L_);
        m2 = *(const i32x4*)(p + 8 * L_);
        m3 = *(const i32x4*)(p + 12 * L_);
    };

    float rS = 0.f;
    float inv = 0.f;

    f32x4 acc[4];   // UNNORMALIZED O accumulator (scaled per-row at end)
    #pragma unroll
    for (int i = 0; i < 4; ++i) acc[i] = (f32x4){0.f, 0.f, 0.f, 0.f};

    // PASS-1 compute: QK, mask bits, exp-sum, unnormalized-e PV
    auto compute1 = [&](const char* KB, const char* VB, int kc,
                        i32x4 m0, i32x4 m1, i32x4 m2, i32x4 m3) {
        auto nib = [](i32x4 m) -> unsigned {
            return (m[0] ? 1u : 0u) | (m[1] ? 2u : 0u) | (m[2] ? 4u : 0u) | (m[3] ? 8u : 0u);
        };
        Mn32[w][l] = nib(m0) | (nib(m1) << 8) | (nib(m2) << 16) | (nib(m3) << 24);
        asm volatile("s_waitcnt lgkmcnt(0)" ::: "memory");  // same-wave xchg
        unsigned mbits = 0;
        const int sh = (lq >> 2) * 8;
        #pragma unroll
        for (int sub = 0; sub < 4; ++sub) {
            unsigned nb = (Mn32[w][(lq & 3) * 16 + sub * 4 + g] >> sh) & 0xFu;
            mbits |= nb << (sub * 4);
        }
        Ml[kc][t] = (unsigned short)mbits;
        float part = 0.f;
        #pragma unroll
        for (int sub = 0; sub < 4; ++sub) {
            bf16x8v a0 = *(const bf16x8v*)(KB + swz(sub * 16 + lq, g * 16));
            bf16x8v a1 = *(const bf16x8v*)(KB + swz(sub * 16 + lq, 64 + g * 16));
            f32x4 s = {0.f, 0.f, 0.f, 0.f};
            s = __builtin_amdgcn_mfma_f32_16x16x32_bf16(a0, qf0, s, 0, 0, 0);
            s = __builtin_amdgcn_mfma_f32_16x16x32_bf16(a1, qf1, s, 0, 0, 0);
            bf16x4v pb;
            #pragma unroll
            for (int r = 0; r < 4; ++r) {
                bool mm = (mbits >> (sub * 4 + r)) & 1u;
                float y = mm ? (fminf(fmaxf(s[r], -15.f), 15.f) - 15.f) : -1e30f;
                float e = __expf(y);      // exp(-1e30) = 0
                part += e;
                pb[r] = (__bf16)e;        // unnormalized
            }
            *(bf16x4v*)(PwB[w] + swz(lq, (sub * 16 + g * 4) * 2)) = pb;
        }
        rS += part;
        // PV with unnormalized e (same-wave LDS RAW)
        #pragma unroll
        for (int ks = 0; ks < 2; ++ks) {
            bf16x8v pa = *(const bf16x8v*)(PwB[w] + swz(lq, ks * 64 + g * 16));
            #pragma unroll
            for (int dt = 0; dt < 4; ++dt) {
                bf16x8v vb = *(const bf16x8v*)(VB + swz(dt * 16 + lq, ks * 64 + g * 16));
                acc[dt] = __builtin_amdgcn_mfma_f32_16x16x32_bf16(pa, vb, acc[dt], 0, 0, 0);
            }
        }
    };

    // PASS-2 compute: QK recompute, attn = e*inv, coalesced NT store. No PV.
    auto compute2 = [&](const char* KB, int kc) {
        const unsigned mbits = Ml[kc][t];
        char* PFw = PfB[w];
        #pragma unroll
        for (int sub = 0; sub < 4; ++sub) {
            bf16x8v a0 = *(const bf16x8v*)(KB + swz(sub * 16 + lq, g * 16));
            bf16x8v a1 = *(const bf16x8v*)(KB + swz(sub * 16 + lq, 64 + g * 16));
            f32x4 s = {0.f, 0.f, 0.f, 0.f};
            s = __builtin_amdgcn_mfma_f32_16x16x32_bf16(a0, qf0, s, 0, 0, 0);
            s = __builtin_amdgcn_mfma_f32_16x16x32_bf16(a1, qf1, s, 0, 0, 0);
            f32x4 pv;
            #pragma unroll
            for (int r = 0; r < 4; ++r) {
                bool mm = (mbits >> (sub * 4 + r)) & 1u;
                float y = mm ? (fminf(fmaxf(s[r], -15.f), 15.f) - 15.f) : -1e30f;
                pv[r] = __expf(y) * inv;
            }
            *(f32x4*)(PFw + swzF(lq, (sub * 16 + g * 4) * 4)) = pv;
        }
        asm volatile("s_waitcnt lgkmcnt(0)" ::: "memory");  // same-wave PFw RAW
        // coalesced NON-TEMPORAL attn store: 4 instrs x (4 rows x 256 B)
        #pragma unroll
        for (int j = 0; j < 4; ++j) {
            const int row = (l >> 4) + 4 * j;
            const int col = (l & 15) * 4;
            f32x4 o = *(const f32x4*)(PFw + swzF(row, col * 4));
            __builtin_nontemporal_store(o, (f32x4*)(attng + (qwrow + row) * L_ + kc * 64 + col));
        }
    };

    // prefetch register sets (A = even tiles, B = odd tiles)
    f32x4 kA0, kA1, kA2, kA3, kB0, kB1, kB2, kB3;
    f32x4 vA0, vA1, vA2, vA3, vB0, vB1, vB2, vB3;
    i32x4 mA0, mA1, mA2, mA3, mB0, mB1, mB2, mB3;

    // ============== PASS 1: exp-sum + unnormalized PV ==============
    loadK(0, kA0, kA1, kA2, kA3);
    loadV(0, vA0, vA1, vA2, vA3);
    loadM(0, mA0, mA1, mA2, mA3);
    writeK(KtB[0], kA0, kA1, kA2, kA3);      // one-time stall
    writeV(VtB[0], vA0, vA1, vA2, vA3);
    loadK(1, kB0, kB1, kB2, kB3);
    loadV(1, vB0, vB1, vB2, vB3);
    loadM(1, mB0, mB1, mB2, mB3);
    bar();
    #pragma unroll 1
    for (int kc = 0; kc < NKC; kc += 2) {
        { int kn = (kc + 2 < NKC) ? kc + 2 : NKC - 1;
          loadK(kn, kA0, kA1, kA2, kA3); loadV(kn, vA0, vA1, vA2, vA3); }
        compute1(KtB[0], VtB[0], kc, mA0, mA1, mA2, mA3);
        { int kn = (kc + 2 < NKC) ? kc + 2 : NKC - 1; loadM(kn, mA0, mA1, mA2, mA3); }
        writeK(KtB[1], kB0, kB1, kB2, kB3);
        writeV(VtB[1], vB0, vB1, vB2, vB3);
        bar();
        { int kn = (kc + 3 < NKC) ? kc + 3 : NKC - 1;
          loadK(kn, kB0, kB1, kB2, kB3); loadV(kn, vB0, vB1, vB2, vB3); }
        compute1(KtB[1], VtB[1], kc + 1, mB0, mB1, mB2, mB3);
        { int kn = (kc + 3 < NKC) ? kc + 3 : NKC - 1; loadM(kn, mB0, mB1, mB2, mB3); }
        writeK(KtB[0], kA0, kA1, kA2, kA3);
        writeV(VtB[0], vA0, vA1, vA2, vA3);
        bar();
    }

    // reduce exp-sum; issue pass-2 first K tile to overlap
    loadK(0, kA0, kA1, kA2, kA3);
    rS += __shfl_xor(rS, 16, 64);
    rS += __shfl_xor(rS, 32, 64);
    inv = 1.f / (rS + 1e-6f);

    // ==================== PASS 2: attn write stream ====================
    writeK(KtB[0], kA0, kA1, kA2, kA3);
    loadK(1, kB0, kB1, kB2, kB3);
    bar();
    #pragma unroll 1
    for (int kc = 0; kc < NKC; kc += 2) {
        { int kn = (kc + 2 < NKC) ? kc + 2 : NKC - 1; loadK(kn, kA0, kA1, kA2, kA3); }
        compute2(KtB[0], kc);
        writeK(KtB[1], kB0, kB1, kB2, kB3);
        bar();
        { int kn = (kc + 3 < NKC) ? kc + 3 : NKC - 1; loadK(kn, kB0, kB1, kB2, kB3); }
        compute2(KtB[1], kc + 1);
        writeK(KtB[0], kA0, kA1, kA2, kA3);
        bar();
    }

    // epilogue: O = acc * inv(row g*4+r)  -- acc row is g*4+r, NOT lq.
    #pragma unroll
    for (int r = 0; r < 4; ++r) {
        const float invR = __shfl(inv, g * 4 + r, 64);  // lane g*4+r has lq==g*4+r
        #pragma unroll
        for (int dt = 0; dt < 4; ++dt) {
            __builtin_nontemporal_store(acc[dt][r] * invR,
                outg + (qwrow + g * 4 + r) * D_ + dt * 16 + lq);
        }
    }
}

extern "C" void kernel_launch(void* const* d_in, const int* in_sizes, int n_in,
                              void* d_out, int out_size, void* d_ws, size_t ws_size,
                              hipStream_t stream) {
    (void)in_sizes; (void)n_in; (void)out_size; (void)d_ws; (void)ws_size;
    const float* q = (const float*)d_in[0];
    const float* k = (const float*)d_in[1];
    const float* v = (const float*)d_in[2];
    const int*   m = (const int*)d_in[3];
    float* out  = (float*)d_out;
    float* attn = out + (size_t)B_ * L_ * D_;
    dim3 grid(B_ * (L_ / 64));   // 512
    dim3 block(256);
    hipLaunchKernelGGL(sdpa_kernel, grid, block, 0, stream, q, k, v, m, out, attn);
}